// Round 1
// baseline (117.955 us; speedup 1.0000x reference)
//
#include <hip/hip_runtime.h>

#define HWZ (128*128*128)   // 2,097,152 voxels per sample
#define NN 2
#define CC 12
#define BLOCK 256
#define GPT 4               // float4-groups per thread
#define BLOCKS_PER_N 512    // 512*256*4 groups *4 voxels = 2,097,152 = HWZ

static constexpr float SMOOTHF = 1e-5f;
static constexpr float BETAF   = 3.0f;

// ws float layout: [0]=ce_sum  [1]=pen_sum
// [2 + n*12 + c]  = inter[n][c]   (24)
// [26 + n*12 + c] = pred[n][c]    (24)
// [50 + n*12 + c] = cnt[n][c]     (24)   -> 74 floats total

__global__ __launch_bounds__(BLOCK) void loss_main(
    const float* __restrict__ in, const int* __restrict__ tgt,
    const float* __restrict__ mat, float* __restrict__ ws)
{
    __shared__ float smat[CC * CC];
    __shared__ float red[4][38];
    const int tid = threadIdx.x;
    if (tid < CC * CC) smat[tid] = mat[tid];
    __syncthreads();

    const int n = blockIdx.y;
    const long base_in = (long)n * CC * HWZ;
    const long base_t  = (long)n * HWZ;

    float ce = 0.f, pen = 0.f;
    float inter[CC], pred[CC], cnt[CC];
    #pragma unroll
    for (int c = 0; c < CC; ++c) { inter[c] = 0.f; pred[c] = 0.f; cnt[c] = 0.f; }

    #pragma unroll
    for (int g = 0; g < GPT; ++g) {
        const int grp = blockIdx.x * (BLOCK * GPT) + g * BLOCK + tid;
        const long s = (long)grp * 4;

        float4 x[CC];
        #pragma unroll
        for (int c = 0; c < CC; ++c)
            x[c] = *reinterpret_cast<const float4*>(in + base_in + (long)c * HWZ + s);
        const int4 t4 = *reinterpret_cast<const int4*>(tgt + base_t + s);

        #pragma unroll
        for (int j = 0; j < 4; ++j) {
            float xv[CC];
            #pragma unroll
            for (int c = 0; c < CC; ++c)
                xv[c] = (j == 0) ? x[c].x : (j == 1) ? x[c].y : (j == 2) ? x[c].z : x[c].w;
            const int t = (j == 0) ? t4.x : (j == 1) ? t4.y : (j == 2) ? t4.z : t4.w;

            float m = xv[0];
            #pragma unroll
            for (int c = 1; c < CC; ++c) m = fmaxf(m, xv[c]);

            float e[CC], sum = 0.f;
            #pragma unroll
            for (int c = 0; c < CC; ++c) { e[c] = __expf(xv[c] - m); sum += e[c]; }
            const float inv = 1.0f / sum;
            const float lse = m + __logf(sum);

            float xt = 0.f, pdot = 0.f;
            const float* row = &smat[t * CC];
            #pragma unroll
            for (int c = 0; c < CC; ++c) {
                const float p = e[c] * inv;
                pred[c] += p;
                const bool hit = (c == t);
                xt       += hit ? xv[c] : 0.f;
                inter[c] += hit ? p     : 0.f;
                cnt[c]   += hit ? 1.f   : 0.f;
                pdot += row[c] * p;
            }
            ce  += lse - xt;
            pen += pdot;
        }
    }

    // pack 38 accumulators, wave-reduce, combine 4 waves in LDS, atomicAdd
    float acc[38];
    acc[0] = ce; acc[1] = pen;
    #pragma unroll
    for (int c = 0; c < CC; ++c) {
        acc[2 + c]  = inter[c];
        acc[14 + c] = pred[c];
        acc[26 + c] = cnt[c];
    }

    const int wave = tid >> 6;
    const int lane = tid & 63;
    #pragma unroll
    for (int k = 0; k < 38; ++k) {
        float v = acc[k];
        #pragma unroll
        for (int off = 32; off >= 1; off >>= 1)
            v += __shfl_xor(v, off, 64);
        if (lane == 0) red[wave][k] = v;
    }
    __syncthreads();

    if (tid < 38) {
        const float s4 = red[0][tid] + red[1][tid] + red[2][tid] + red[3][tid];
        int gidx;
        if (tid < 2)       gidx = tid;                        // ce, pen (global)
        else if (tid < 14) gidx = 2  + n * CC + (tid - 2);    // inter
        else if (tid < 26) gidx = 26 + n * CC + (tid - 14);   // pred
        else               gidx = 50 + n * CC + (tid - 26);   // cnt
        atomicAdd(&ws[gidx], s4);
    }
}

__global__ void loss_final(const float* __restrict__ ws, float* __restrict__ out)
{
    const float V = (float)((long)NN * HWZ);
    const float ce  = ws[0] / V;
    const float pen = BETAF * ws[1] / V;
    float dice = 0.f;
    for (int i = 0; i < NN * CC; ++i) {
        const float it = ws[2 + i], pr = ws[26 + i], ct = ws[50 + i];
        dice += 1.f - (2.f * it + SMOOTHF) / (ct + pr + SMOOTHF);
    }
    dice *= (1.0f / (NN * CC));
    out[0] = ce + dice + pen;
}

extern "C" void kernel_launch(void* const* d_in, const int* in_sizes, int n_in,
                              void* d_out, int out_size, void* d_ws, size_t ws_size,
                              hipStream_t stream)
{
    const float* in  = (const float*)d_in[0];
    const int*   tgt = (const int*)d_in[1];
    const float* mat = (const float*)d_in[2];
    float* ws  = (float*)d_ws;
    float* out = (float*)d_out;

    hipMemsetAsync(ws, 0, 74 * sizeof(float), stream);
    dim3 grid(BLOCKS_PER_N, NN);
    loss_main<<<grid, BLOCK, 0, stream>>>(in, tgt, mat, ws);
    loss_final<<<1, 1, 0, stream>>>(ws, out);
}

// Round 2
// 62.301 us; speedup vs baseline: 1.8933x; 1.8933x over previous
//
#include <hip/hip_runtime.h>

#define HWZ (128*128*128)   // 2,097,152 voxels per sample
#define NN 2
#define CC 12
#define BLOCK 256
#define BLOCKS_PER_N 1024
#define GPT 4               // float2-groups per thread: 1024*256*4*2 = HWZ
#define NREP 8              // replicated accumulator sets to spread atomics

static constexpr float SMOOTHF = 1e-5f;
static constexpr float BETAF   = 3.0f;

// ws layout: NREP replicas of 74 floats:
// [0]=ce [1]=pen
// [2  + n*12 + c] = inter[n][c]
// [26 + n*12 + c] = pred[n][c]
// [50 + n*12 + c] = cnt[n][c]

__global__ __launch_bounds__(BLOCK) void loss_main(
    const float* __restrict__ in, const int* __restrict__ tgt,
    const float* __restrict__ mat, float* __restrict__ ws)
{
    __shared__ float smat[CC * CC];
    __shared__ float red[4][38];
    const int tid = threadIdx.x;
    if (tid < CC * CC) smat[tid] = mat[tid];
    __syncthreads();

    const int n = blockIdx.y;
    const float* __restrict__ inb = in + (size_t)n * CC * HWZ;
    const int*   __restrict__ tb  = tgt + (size_t)n * HWZ;

    float ce = 0.f, pen = 0.f;
    float inter[CC], pred[CC];
    unsigned long long cnt_pack = 0ull;   // 12 x 4-bit counters (max 8 each)
    #pragma unroll
    for (int c = 0; c < CC; ++c) { inter[c] = 0.f; pred[c] = 0.f; }

    #pragma unroll 1
    for (int g = 0; g < GPT; ++g) {
        const int grp = g * (BLOCKS_PER_N * BLOCK) + blockIdx.x * BLOCK + tid;
        const size_t s = (size_t)grp * 2;

        float2 x[CC];
        #pragma unroll
        for (int c = 0; c < CC; ++c)
            x[c] = *reinterpret_cast<const float2*>(inb + (size_t)c * HWZ + s);
        const int2 t2 = *reinterpret_cast<const int2*>(tb + s);

        #pragma unroll
        for (int j = 0; j < 2; ++j) {
            float xv[CC];
            #pragma unroll
            for (int c = 0; c < CC; ++c) xv[c] = (j == 0) ? x[c].x : x[c].y;
            const int t = (j == 0) ? t2.x : t2.y;

            float m = xv[0];
            #pragma unroll
            for (int c = 1; c < CC; ++c) m = fmaxf(m, xv[c]);

            float e[CC], sum = 0.f;
            #pragma unroll
            for (int c = 0; c < CC; ++c) { e[c] = __expf(xv[c] - m); sum += e[c]; }
            const float inv = 1.0f / sum;
            const float lse = m + __logf(sum);

            float xt = 0.f, pdot = 0.f;
            const float* row = &smat[t * CC];
            #pragma unroll
            for (int c = 0; c < CC; ++c) {
                const float p = e[c] * inv;
                pred[c] += p;
                const bool hit = (c == t);
                xt       += hit ? xv[c] : 0.f;
                inter[c] += hit ? p     : 0.f;
                pdot     += row[c] * p;
            }
            cnt_pack += 1ull << (t * 4);
            ce  += lse - xt;
            pen += pdot;
        }
    }

    // pack 38 accumulators, wave-reduce, combine 4 waves, replicated atomicAdd
    float acc[38];
    acc[0] = ce; acc[1] = pen;
    #pragma unroll
    for (int c = 0; c < CC; ++c) {
        acc[2 + c]  = inter[c];
        acc[14 + c] = pred[c];
        acc[26 + c] = (float)((cnt_pack >> (c * 4)) & 15ull);
    }

    const int wave = tid >> 6;
    const int lane = tid & 63;
    #pragma unroll
    for (int k = 0; k < 38; ++k) {
        float v = acc[k];
        #pragma unroll
        for (int off = 32; off >= 1; off >>= 1)
            v += __shfl_xor(v, off, 64);
        if (lane == 0) red[wave][k] = v;
    }
    __syncthreads();

    if (tid < 38) {
        const float s4 = red[0][tid] + red[1][tid] + red[2][tid] + red[3][tid];
        int gidx;
        if (tid < 2)       gidx = tid;
        else if (tid < 14) gidx = 2  + n * CC + (tid - 2);
        else if (tid < 26) gidx = 26 + n * CC + (tid - 14);
        else               gidx = 50 + n * CC + (tid - 26);
        const int r = blockIdx.x & (NREP - 1);
        atomicAdd(&ws[r * 74 + gidx], s4);
    }
}

__global__ void loss_final(const float* __restrict__ ws, float* __restrict__ out)
{
    __shared__ float agg[74];
    const int tid = threadIdx.x;
    if (tid < 74) {
        float s = 0.f;
        #pragma unroll
        for (int r = 0; r < NREP; ++r) s += ws[r * 74 + tid];
        agg[tid] = s;
    }
    __syncthreads();
    if (tid == 0) {
        const float V = (float)((long)NN * HWZ);
        const float ce  = agg[0] / V;
        const float pen = BETAF * agg[1] / V;
        float dice = 0.f;
        for (int i = 0; i < NN * CC; ++i) {
            const float it = agg[2 + i], pr = agg[26 + i], ct = agg[50 + i];
            dice += 1.f - (2.f * it + SMOOTHF) / (ct + pr + SMOOTHF);
        }
        dice *= (1.0f / (NN * CC));
        out[0] = ce + dice + pen;
    }
}

extern "C" void kernel_launch(void* const* d_in, const int* in_sizes, int n_in,
                              void* d_out, int out_size, void* d_ws, size_t ws_size,
                              hipStream_t stream)
{
    const float* in  = (const float*)d_in[0];
    const int*   tgt = (const int*)d_in[1];
    const float* mat = (const float*)d_in[2];
    float* ws  = (float*)d_ws;
    float* out = (float*)d_out;

    hipMemsetAsync(ws, 0, NREP * 74 * sizeof(float), stream);
    dim3 grid(BLOCKS_PER_N, NN);
    loss_main<<<grid, BLOCK, 0, stream>>>(in, tgt, mat, ws);
    loss_final<<<1, 128, 0, stream>>>(ws, out);
}